// Round 6
// baseline (24.630 us; speedup 1.0000x reference)
//
#include <hip/hip_runtime.h>

#define N 512
#define D 128

// ws layout:
//   float  XT[2][128][512]            512 KB  transposed src/tgt (planar)
//   ull    rs_bits[2][512]            8 KB    complete row-sums (double bits)
//   ull    ss_bits[2][512]            8 KB    complete row sum-of-squares
//   int    counter                    4 B     last-block ticket

__device__ __forceinline__ double wave_reduce_add(double v) {
    #pragma unroll
    for (int off = 32; off > 0; off >>= 1)
        v += __shfl_down(v, off, 64);
    return v;
}

// K0: LDS-tiled transpose. 128 blocks: m(2) x dtile(4) x jtile(16), 32x32 tiles.
// Also zeroes the ticket counter (stream-ordered before K1).
__global__ __launch_bounds__(256) void gw_transpose(
    const float* __restrict__ src, const float* __restrict__ tgt,
    float* __restrict__ XT, int* __restrict__ counter)
{
    if (blockIdx.x == 0 && threadIdx.x == 0) *counter = 0;

    __shared__ float ld[32][33];
    const int b  = blockIdx.x;
    const int m  = b >> 6;
    const int dt = (b >> 4) & 3;
    const int jt = b & 15;
    const float* X = m ? tgt : src;
    float* XTm = XT + m * (D * N);

    const int t = threadIdx.x;
    const int c = t & 31;
    const int r = t >> 5;

    #pragma unroll
    for (int p = 0; p < 4; ++p) {
        int jr = r + p * 8;
        ld[jr][c] = X[(jt * 32 + jr) * D + dt * 32 + c];   // coalesced read
    }
    __syncthreads();
    #pragma unroll
    for (int p = 0; p < 4; ++p) {
        int dr = r + p * 8;
        XTm[(dt * 32 + dr) * N + jt * 32 + c] = ld[c][dr]; // conflict-free, coalesced write
    }
}

// K1: 256 blocks x 512 threads. Block b = (m = b>>7, iq = b&127) owns rows
// i0..i0+3 of ONE matrix over the FULL j-range (thread tid = j). Publishes
// complete rs/ss for its 4 rows via device-scope atomicExch (executes at the
// L3 coherence point), then the last-ticket block finalizes with PLAIN loads
// (its L1/L2 hold no copies of these lines: kernel-begin invalidate + no
// prior touch this kernel -> loads miss to L3 and see the exchanged values).
__global__ __launch_bounds__(512) void gw_distfin(
    const float* __restrict__ src, const float* __restrict__ tgt,
    const float* __restrict__ XT,
    unsigned long long* __restrict__ rs_bits,
    unsigned long long* __restrict__ ss_bits,
    int* __restrict__ counter, float* __restrict__ out)
{
    const int b   = blockIdx.x;
    const int m   = b >> 7;
    const int iq  = b & 127;
    const int i0  = iq * 4;
    const int tid = threadIdx.x;   // j

    const float* X   = m ? tgt : src;
    const float* XTm = XT + m * (D * N);
    const float* r0  = X + (i0 + 0) * D;   // wave-uniform rows -> scalar loads
    const float* r1  = X + (i0 + 1) * D;
    const float* r2  = X + (i0 + 2) * D;
    const float* r3  = X + (i0 + 3) * D;

    float a0 = 0.f, a1 = 0.f, a2 = 0.f, a3 = 0.f;
    #pragma unroll 8
    for (int d = 0; d < D; ++d) {
        float v = XTm[d * N + tid];        // coalesced: lane stride 4B
        float e;
        e = r0[d] - v; a0 += e * e;
        e = r1[d] - v; a1 += e * e;
        e = r2[d] - v; a2 += e * e;
        e = r3[d] - v; a3 += e * e;
    }

    // one pair per (thread, i): a* are exact f32 pair-costs; all j-summation
    // happens in double below (identical math to validated rounds).
    double q[8];
    q[0] = (double)a0; q[1] = (double)a1; q[2] = (double)a2; q[3] = (double)a3;
    q[4] = (double)a0 * (double)a0;
    q[5] = (double)a1 * (double)a1;
    q[6] = (double)a2 * (double)a2;
    q[7] = (double)a3 * (double)a3;

    __shared__ double red[8][8];           // [wave][quantity]
    __shared__ int islast;
    const int wave = tid >> 6;
    const int lane = tid & 63;
    #pragma unroll
    for (int k = 0; k < 8; ++k) {
        double v = wave_reduce_add(q[k]);
        if (lane == 0) red[wave][k] = v;
    }
    __syncthreads();

    if (tid == 0) {
        unsigned long long olds[8];
        #pragma unroll
        for (int k = 0; k < 4; ++k) {
            double rs = 0.0, ss = 0.0;
            #pragma unroll
            for (int w = 0; w < 8; ++w) { rs += red[w][k]; ss += red[w][k + 4]; }
            olds[k]     = atomicExch(&rs_bits[m * N + i0 + k],
                                     (unsigned long long)__double_as_longlong(rs));
            olds[k + 4] = atomicExch(&ss_bits[m * N + i0 + k],
                                     (unsigned long long)__double_as_longlong(ss));
        }
        // consume returned values: forces s_waitcnt vmcnt(0), so all 8
        // exchanges have completed at the L3 before the ticket increments.
        asm volatile("" :: "v"(olds[0]), "v"(olds[1]), "v"(olds[2]), "v"(olds[3]),
                           "v"(olds[4]), "v"(olds[5]), "v"(olds[6]), "v"(olds[7])
                     : "memory");
        int ticket = atomicAdd(counter, 1);
        islast = (ticket == (int)gridDim.x - 1);
    }
    __syncthreads();

    if (islast) {
        // plain (volatile, L1-bypass) loads -- NOT RMWs. 16 KB from L3.
        const int i = tid;
        volatile const unsigned long long* rsv = rs_bits;
        volatile const unsigned long long* ssv = ss_bits;
        double rs_s = __longlong_as_double((long long)rsv[0 * N + i]);
        double rs_t = __longlong_as_double((long long)rsv[1 * N + i]);
        double ss_s = __longlong_as_double((long long)ssv[0 * N + i]);
        double ss_t = __longlong_as_double((long long)ssv[1 * N + i]);

        double v = (double)N * (ss_s + ss_t) - 2.0 * rs_s * rs_t;
        v = wave_reduce_add(v);
        if (lane == 0) red[wave][0] = v;
        __syncthreads();
        if (tid == 0) {
            double total = 0.0;
            #pragma unroll
            for (int w = 0; w < 8; ++w) total += red[w][0];
            out[0] = (float)(total / ((double)N * (double)N));
        }
    }
}

extern "C" void kernel_launch(void* const* d_in, const int* in_sizes, int n_in,
                              void* d_out, int out_size, void* d_ws, size_t ws_size,
                              hipStream_t stream) {
    const float* src = (const float*)d_in[0];
    const float* tgt = (const float*)d_in[1];
    float* out = (float*)d_out;

    char* w = (char*)d_ws;
    float*              XT      = (float*)w;                                   // 512 KB
    unsigned long long* rs_bits = (unsigned long long*)(w + 2 * D * N * 4);    // 8 KB
    unsigned long long* ss_bits = (unsigned long long*)(w + 2 * D * N * 4 + 2 * N * 8);
    int*                counter = (int*)(w + 2 * D * N * 4 + 4 * N * 8);

    gw_transpose<<<dim3(128), dim3(256), 0, stream>>>(src, tgt, XT, counter);
    gw_distfin  <<<dim3(256), dim3(512), 0, stream>>>(src, tgt, XT, rs_bits, ss_bits,
                                                      counter, out);
}